// Round 3
// baseline (268.530 us; speedup 1.0000x reference)
//
#include <hip/hip_runtime.h>
#include <hip/hip_bf16.h>

#define B_   4
#define NX_  1024
#define NC_  2048
#define C_   1024
#define H_   16
#define DH_  64

typedef __attribute__((ext_vector_type(8))) __bf16 bf16x8;
typedef __attribute__((ext_vector_type(4))) float  f32x4;

// RNE float->bf16 (inputs finite)
static __device__ __forceinline__ unsigned short f2bf(float f) {
    unsigned int u = __float_as_uint(f);
    u += 0x7fffu + ((u >> 16) & 1u);
    return (unsigned short)(u >> 16);
}

// pack 2 floats -> 2 bf16 (round-half-up): {lo in bits 0-15, hi in 16-31}
static __device__ __forceinline__ unsigned int pk2(float lo, float hi) {
    unsigned int a = __float_as_uint(lo) + 0x8000u;
    unsigned int b = __float_as_uint(hi) + 0x8000u;
    return __builtin_amdgcn_perm(b, a, 0x07060302);   // {b.hi16, a.hi16}
}

// 1-instr pack (RNE): dst.lo16 = bf16(lo), dst.hi16 = bf16(hi)
static __device__ __forceinline__ unsigned int cvtpk(float lo, float hi) {
    unsigned int r;
    asm("v_cvt_pk_bf16_f32 %0, %1, %2" : "=v"(r) : "v"(lo), "v"(hi));
    return r;
}

static __device__ __forceinline__ bf16x8 ldfrag(const unsigned short* p) {
    union { uint4 u; bf16x8 b; } cv;
    cv.u = *reinterpret_cast<const uint4*>(p);
    return cv.b;
}

#define AS1 __attribute__((address_space(1)))
#define AS3 __attribute__((address_space(3)))
// async global->LDS, 16B/lane; lptr wave-uniform base, HW writes lane i at lptr + i*16
static __device__ __forceinline__ void gload16(const unsigned short* g, unsigned short* l) {
    __builtin_amdgcn_global_load_lds((const AS1 void*)g, (AS3 void*)l, 16, 0, 0);
}

// sigma: key-chunk c (4 keys) -> storage slot position within its 32-key group.
// vt is stored SLOT-ORDERED so attn's PV B-fragment (pk2 of QK C-layout) matches
// a LINEAR V read: slot 2c <- chunk c (c<4), slot 2c-7 <- chunk c (c>=4).

// ---------------- merged converts: x, w_qkv, w_proj, cache_k (flat) + cache_v (transpose+slot-permute) ----------------
__global__ __launch_bounds__(256) void cvt_all_kernel(
    const float* __restrict__ x,  const float* __restrict__ wq,
    const float* __restrict__ wp, const float* __restrict__ ck,
    const float* __restrict__ cv_,
    unsigned short* __restrict__ xbf,  unsigned short* __restrict__ wqbf,
    unsigned short* __restrict__ wpbf, unsigned short* __restrict__ kfb,
    unsigned short* __restrict__ vt) {
    int blk = blockIdx.x;
    if (blk < 16384) {
        const float* src; unsigned short* dst; int i;
        if (blk < 4096)      { src = x;  dst = xbf;  i = blk; }
        else if (blk < 7168) { src = wq; dst = wqbf; i = blk - 4096; }
        else if (blk < 8192) { src = wp; dst = wpbf; i = blk - 7168; }
        else                 { src = ck; dst = kfb;  i = blk - 8192; }
        int idx = i * 256 + threadIdx.x;
        float4 f = reinterpret_cast<const float4*>(src)[idx];
        ushort4 o;
        o.x = f2bf(f.x); o.y = f2bf(f.y); o.z = f2bf(f.z); o.w = f2bf(f.w);
        reinterpret_cast<ushort4*>(dst)[idx] = o;
    } else {
        int i   = blk - 16384;       // 0..4095
        int t   = threadIdx.x;
        int bh  = i >> 6;
        int kg  = i & 63;
        int d   = t & 63;
        int kci = t >> 6;
        int kc  = kg * 4 + kci;      // 8-key chunk index (keys kc*8..+7)
        const float* src = cv_ + ((size_t)bh * NC_ + (size_t)kc * 8) * DH_ + d;
        union { uint4 u; unsigned short s[8]; } o;
#pragma unroll
        for (int j = 0; j < 8; j++) o.s[j] = f2bf(src[(size_t)j * DH_]);
        // slot-permuted write: group = kc>>2, local 4-key chunks 2m,2m+1 (m=kc&3)
        // -> positions sigma(2m)=pos0, sigma(2m+1)=pos0+2
        int m = kc & 3;
        int pos0 = (m < 2) ? 4 * m : 4 * m - 7;
        unsigned short* vb = vt + ((size_t)bh * DH_ + d) * NC_ + (kc >> 2) * 32 + pos0 * 4;
        uint2 lo2; lo2.x = o.u.x; lo2.y = o.u.y;
        uint2 hi2; hi2.x = o.u.z; hi2.y = o.u.w;
        *reinterpret_cast<uint2*>(vb)     = lo2;
        *reinterpret_cast<uint2*>(vb + 8) = hi2;
    }
}

#define LSTR 40

// ---------------- QKV GEMM (4096x1024)x(3072x1024)^T, 128x128 tile + scatter ----------------
__global__ __launch_bounds__(256, 3) void qkv_gemm_kernel(
    const unsigned short* __restrict__ xbf,
    const unsigned short* __restrict__ wbf,
    const float* __restrict__ bias,
    const int* __restrict__ uidx,
    unsigned short* __restrict__ qb,   // (B,H,NX,DH) scaled by 0.125*log2(e)
    unsigned short* __restrict__ kf,   // (B,H,NC,DH)
    unsigned short* __restrict__ vt)   // (B,H,DH,NC) slot-permuted within 32-key groups
{
    __shared__ unsigned short As[128 * LSTR], Bs[128 * LSTR];
    __shared__ int jtab[128];
    int bn = blockIdx.x, bm = blockIdx.y;
    int w = threadIdx.x >> 6, l = threadIdx.x & 63;
    int quad = l >> 4, col = l & 15;
    int wr = w >> 1, wc = w & 1;
    int srow = w * 32 + (l >> 2), schk = (l & 3) * 8;

    const unsigned short* Ap = xbf + (size_t)(bm * 128 + srow) * C_ + schk;
    const unsigned short* Bp = wbf + (size_t)(bn * 128 + srow) * C_ + schk;
    unsigned short* Aw = As + srow * LSTR + schk;
    unsigned short* Bw = Bs + srow * LSTR + schk;

    f32x4 acc[4][4];
#pragma unroll
    for (int a = 0; a < 4; a++)
#pragma unroll
        for (int b = 0; b < 4; b++) acc[a][b] = (f32x4){0.f, 0.f, 0.f, 0.f};

    uint4 ar0, ar1, br0, br1;
#define LDREG(kk_)                                                       \
    {   int kk = (kk_) * 32;                                             \
        ar0 = *reinterpret_cast<const uint4*>(Ap + kk);                  \
        ar1 = *reinterpret_cast<const uint4*>(Ap + 16 * C_ + kk);        \
        br0 = *reinterpret_cast<const uint4*>(Bp + kk);                  \
        br1 = *reinterpret_cast<const uint4*>(Bp + 16 * C_ + kk);        \
    }
#define WRTILE()                                                         \
    {   *reinterpret_cast<uint4*>(Aw)             = ar0;                 \
        *reinterpret_cast<uint4*>(Aw + 16 * LSTR) = ar1;                 \
        *reinterpret_cast<uint4*>(Bw)             = br0;                 \
        *reinterpret_cast<uint4*>(Bw + 16 * LSTR) = br1;                 \
    }

    LDREG(0);
    WRTILE();
    LDREG(1);
    __syncthreads();
#pragma unroll 1
    for (int it = 0; it < 32; it++) {
        bf16x8 af[4], bfr[4];
#pragma unroll
        for (int t = 0; t < 4; t++) af[t]  = ldfrag(&As[(wr * 64 + t * 16 + col) * LSTR + quad * 8]);
#pragma unroll
        for (int t = 0; t < 4; t++) bfr[t] = ldfrag(&Bs[(wc * 64 + t * 16 + col) * LSTR + quad * 8]);
#pragma unroll
        for (int mt = 0; mt < 4; mt++)
#pragma unroll
            for (int nt = 0; nt < 4; nt++)
                acc[mt][nt] = __builtin_amdgcn_mfma_f32_16x16x32_bf16(af[mt], bfr[nt], acc[mt][nt], 0, 0, 0);
        if (it < 31) {
            __syncthreads();
            WRTILE();
            LDREG(it + 2 < 31 ? it + 2 : 31);
            __syncthreads();
        }
    }
#undef LDREG
#undef WRTILE

    int part = bn >> 3;             // 0=q 1=k 2=v
    float bv[4];
#pragma unroll
    for (int nt = 0; nt < 4; nt++) bv[nt] = bias[bn * 128 + wc * 64 + nt * 16 + col];

    if (part <= 1) {
        int nl[4];
#pragma unroll
        for (int nt = 0; nt < 4; nt++) nl[nt] = (bn * 128 + wc * 64 + nt * 16 + col) & 1023;
        const float QS = 0.18033688011112042f;   // 0.125 * log2(e)
#pragma unroll
        for (int mt = 0; mt < 4; mt++)
#pragma unroll
            for (int r = 0; r < 4; r++) {
                int m = bm * 128 + wr * 64 + mt * 16 + quad * 4 + r;
                int b = m >> 10, i = m & 1023;
                int j = (part == 0) ? 0 : uidx[m];
#pragma unroll
                for (int nt = 0; nt < 4; nt++) {
                    int h = nl[nt] >> 6, d = nl[nt] & 63;
                    float v = acc[mt][nt][r] + bv[nt];
                    if (part == 0)
                        qb[((size_t)(b * H_ + h) * NX_ + i) * DH_ + d] = f2bf(v * QS);
                    else
                        kf[((size_t)(b * H_ + h) * NC_ + j) * DH_ + d] = f2bf(v);
                }
            }
    } else {
        // ---- V-part: LDS transpose + token-major scatter (slot-permuted position) ----
        if (threadIdx.x < 128) jtab[threadIdx.x] = uidx[bm * 128 + threadIdx.x];
        __syncthreads();   // jtab ready; As/Bs reads from main loop done
        int h = ((bn * 128 + wc * 64) & 1023) >> 6;   // const per wave (64-aligned)
        int b = (bm * 128) >> 10;
        unsigned short* T = (wc == 0) ? As : Bs;      // 64 x 72 bf16 (9216 B)
        int jv = jtab[wr * 64 + l];
        int c_ = (jv >> 2) & 7;
        int sp = (c_ < 4) ? 2 * c_ : 2 * c_ - 7;
        int jp = (jv & ~31) | (sp << 2) | (jv & 3);   // sigma-permuted position
        unsigned short* vb2 = vt + ((size_t)(b * H_ + h) * 64) * NC_ + jp;
#pragma unroll 1
        for (int round = 0; round < 2; round++) {
            if (wr == round) {
#pragma unroll
                for (int nt = 0; nt < 4; nt++)
#pragma unroll
                    for (int mt = 0; mt < 4; mt++) {
                        uint2 pk;
                        pk.x = pk2(acc[mt][nt][0] + bv[nt], acc[mt][nt][1] + bv[nt]);
                        pk.y = pk2(acc[mt][nt][2] + bv[nt], acc[mt][nt][3] + bv[nt]);
                        *reinterpret_cast<uint2*>(&T[(nt * 16 + col) * 72 + mt * 16 + quad * 4]) = pk;
                    }
                asm volatile("s_waitcnt lgkmcnt(0)" ::: "memory");
#pragma unroll 1
                for (int d = 0; d < 64; d++)
                    vb2[(size_t)d * NC_] = T[d * 72 + l];   // lanes = 64 sorted tokens
            }
            __syncthreads();
        }
    }
}

// ---------------- flash attention v4: disjoint-key waves + global_load_lds + 1 barrier/step ----------------
// R1 post-mortem: remaining stall = bulk LDS tile traffic (48KB per 64-key step: frag
// reads duplicated across qh-paired waves) + 2 barriers/step. v4: 128-key tiles, each
// of 4 waves owns a DISJOINT 32-key slice and all 64 q -> LDS reads halved (no dup).
// Staging via global_load_lds w=16 into linear unpadded [row][32] LDS (vt slot-
// pre-permuted by producers so V staging is a linear copy). Double-buffered tiles,
// ONE barrier per step (16 steps). l_i via ones-row MFMA (VALU->MFMA, kills serial
// add chain + shfl reduce); P packed with v_cvt_pk_bf16_f32 (1 op vs 3).
__global__ __launch_bounds__(256, 2) void attn_kernel(
    const unsigned short* __restrict__ qb,
    const unsigned short* __restrict__ kf,
    const unsigned short* __restrict__ vt,
    unsigned short* __restrict__ ao)          // (B,NX,C) bf16
{
    __shared__ __align__(16) unsigned short smem[2][16384];  // 64KB: per buf {Klo 8KB, Khi 8KB, V 16KB}
    float* Om = (float*)&smem[0][0];                          // epilogue alias: [64 rows][64 lanes]
    float* Lm = Om + 64 * 64;                                 // [64 q]

    int id = blockIdx.x;
    int qt = (id >> 3) & 15;               // 0..15
    int bh = ((id >> 7) << 3) | (id & 7);  // 0..63, id%8 == bh%8 (XCD locality)
    int w = threadIdx.x >> 6, lane = threadIdx.x & 63;
    int quad = lane >> 4, col = lane & 15;

    // Q fragments: 4 q-16-tiles x 2 dh-halves (all 64 q of this block)
    const unsigned short* qp = qb + ((size_t)bh * NX_ + qt * 64 + col) * DH_ + quad * 8;
    bf16x8 qf[4][2];
#pragma unroll
    for (int nt = 0; nt < 4; nt++) {
        qf[nt][0] = ldfrag(qp + nt * 16 * DH_);
        qf[nt][1] = ldfrag(qp + nt * 16 * DH_ + 32);
    }

    // staging sources (per-lane): wave w owns keys [t*128 + w*32, +32)
    const unsigned short* Kp = kf + ((size_t)bh * NC_ + w * 32 + (lane >> 2)) * DH_ + (lane & 3) * 8;
    const unsigned short* Vp = vt + ((size_t)bh * DH_ + (lane >> 2)) * NC_ + w * 32 + (lane & 3) * 8;

    f32x4 o[4][4];
#pragma unroll
    for (int m = 0; m < 4; m++)
#pragma unroll
        for (int n = 0; n < 4; n++) o[m][n] = (f32x4){0.f, 0.f, 0.f, 0.f};
    f32x4 lacc[4];
#pragma unroll
    for (int n = 0; n < 4; n++) lacc[n] = (f32x4){0.f, 0.f, 0.f, 0.f};
    bf16x8 onef;
    { union { unsigned int u[4]; bf16x8 b; } c1;
      c1.u[0] = c1.u[1] = c1.u[2] = c1.u[3] = 0x3F803F80u; onef = c1.b; }

    // stage tile t_ into buffer bi: 8 x global_load_lds per wave (4 K + 4 V), all linear
    auto stage = [&](int bi, int t_) {
        unsigned short* Kl = &smem[bi][w * 1024];           // rows w*32.., 32 shorts/row
        unsigned short* Kh = &smem[bi][4096 + w * 1024];
        unsigned short* Vd = &smem[bi][8192 + w * 2048];    // group w: [64 dh][32 keys]
        const unsigned short* kg = Kp + (size_t)t_ * (128 * DH_);
        const unsigned short* vg = Vp + t_ * 128;
        gload16(kg,                Kl);
        gload16(kg + 16 * DH_,     Kl + 512);
        gload16(kg + 32,           Kh);
        gload16(kg + 16 * DH_ + 32, Kh + 512);
        gload16(vg,                Vd);
        gload16(vg + 16 * NC_,     Vd + 512);
        gload16(vg + 32 * NC_,     Vd + 1024);
        gload16(vg + 48 * NC_,     Vd + 1536);
    };

    auto compute = [&](int bi) {
        const unsigned short* Kl = &smem[bi][0];
        const unsigned short* Kh = &smem[bi][4096];
        const unsigned short* Vv = &smem[bi][8192];
        int kr0 = (w * 32 + col) * 32 + quad * 8;
        bf16x8 ka0 = ldfrag(&Kl[kr0]);
        bf16x8 kh0 = ldfrag(&Kh[kr0]);
        bf16x8 ka1 = ldfrag(&Kl[kr0 + 512]);   // +16 rows
        bf16x8 kh1 = ldfrag(&Kh[kr0 + 512]);
        bf16x8 vfr[4];
#pragma unroll
        for (int m4 = 0; m4 < 4; m4++)
            vfr[m4] = ldfrag(&Vv[(w * 64 + m4 * 16 + col) * 32 + quad * 8]);
        // ---- S^T = K.Q^T : 32 keys x 64 q ----
        f32x4 s[2][4];
#pragma unroll
        for (int nt = 0; nt < 4; nt++) {
            s[0][nt] = (f32x4){0.f, 0.f, 0.f, 0.f};
            s[1][nt] = (f32x4){0.f, 0.f, 0.f, 0.f};
            s[0][nt] = __builtin_amdgcn_mfma_f32_16x16x32_bf16(ka0, qf[nt][0], s[0][nt], 0, 0, 0);
            s[0][nt] = __builtin_amdgcn_mfma_f32_16x16x32_bf16(kh0, qf[nt][1], s[0][nt], 0, 0, 0);
            s[1][nt] = __builtin_amdgcn_mfma_f32_16x16x32_bf16(ka1, qf[nt][0], s[1][nt], 0, 0, 0);
            s[1][nt] = __builtin_amdgcn_mfma_f32_16x16x32_bf16(kh1, qf[nt][1], s[1][nt], 0, 0, 0);
        }
        // ---- no-max softmax (log2 domain) -> PV B-fragments in registers ----
        bf16x8 pf[4];
#pragma unroll
        for (int nt = 0; nt < 4; nt++) {
            float e0 = exp2f(s[0][nt][0]), e1 = exp2f(s[0][nt][1]);
            float e2 = exp2f(s[0][nt][2]), e3 = exp2f(s[0][nt][3]);
            float e4 = exp2f(s[1][nt][0]), e5 = exp2f(s[1][nt][1]);
            float e6 = exp2f(s[1][nt][2]), e7 = exp2f(s[1][nt][3]);
            union { unsigned int u[4]; bf16x8 b; } pw;
            pw.u[0] = cvtpk(e0, e1); pw.u[1] = cvtpk(e2, e3);
            pw.u[2] = cvtpk(e4, e5); pw.u[3] = cvtpk(e6, e7);
            pf[nt] = pw.b;
        }
        // ---- l via ones-row MFMA; O^T += V^T . P^T ----
#pragma unroll
        for (int nt = 0; nt < 4; nt++)
            lacc[nt] = __builtin_amdgcn_mfma_f32_16x16x32_bf16(onef, pf[nt], lacc[nt], 0, 0, 0);
#pragma unroll
        for (int m4 = 0; m4 < 4; m4++)
#pragma unroll
            for (int nt = 0; nt < 4; nt++)
                o[m4][nt] = __builtin_amdgcn_mfma_f32_16x16x32_bf16(vfr[m4], pf[nt], o[m4][nt], 0, 0, 0);
    };

    stage(0, 0);
    __syncthreads();
#pragma unroll 1
    for (int t2 = 0; t2 < 8; t2++) {
        int t = t2 << 1;
        stage(1, t + 1);
        compute(0);
        __syncthreads();
        if (t + 2 < 16) stage(0, t + 2);
        compute(1);
        __syncthreads();
    }

    float l_i[4];
#pragma unroll
    for (int nt = 0; nt < 4; nt++) l_i[nt] = lacc[nt][0];   // all rows equal (ones-MFMA)

    // ---- merge 4 disjoint key-range partials: plain (O,l) addition (m==0 softmax) ----
    if (w == 3) {
#pragma unroll
        for (int mt = 0; mt < 4; mt++)
#pragma unroll
            for (int nt = 0; nt < 4; nt++)
#pragma unroll
                for (int r = 0; r < 4; r++)
                    Om[((mt * 4 + nt) * 4 + r) * 64 + lane] = o[mt][nt][r];
        if (quad == 0)
#pragma unroll
            for (int nt = 0; nt < 4; nt++) Lm[nt * 16 + col] = l_i[nt];
    }
    __syncthreads();
    if (w == 2) {
#pragma unroll
        for (int mt = 0; mt < 4; mt++)
#pragma unroll
            for (int nt = 0; nt < 4; nt++)
#pragma unroll
                for (int r = 0; r < 4; r++)
                    Om[((mt * 4 + nt) * 4 + r) * 64 + lane] += o[mt][nt][r];
        if (quad == 0)
#pragma unroll
            for (int nt = 0; nt < 4; nt++) Lm[nt * 16 + col] += l_i[nt];
    }
    __syncthreads();
    if (w == 1) {
#pragma unroll
        for (int mt = 0; mt < 4; mt++)
#pragma unroll
            for (int nt = 0; nt < 4; nt++)
#pragma unroll
                for (int r = 0; r < 4; r++)
                    Om[((mt * 4 + nt) * 4 + r) * 64 + lane] += o[mt][nt][r];
        if (quad == 0)
#pragma unroll
            for (int nt = 0; nt < 4; nt++) Lm[nt * 16 + col] += l_i[nt];
    }
    __syncthreads();
    if (w == 0) {
        float inv[4];
#pragma unroll
        for (int nt = 0; nt < 4; nt++)
            inv[nt] = 1.f / (l_i[nt] + Lm[nt * 16 + col]);
        int b = bh >> 4, h = bh & 15;
#pragma unroll
        for (int mt = 0; mt < 4; mt++)
#pragma unroll
            for (int nt = 0; nt < 4; nt++) {
                int base = ((mt * 4 + nt) * 4) * 64 + lane;
                float v0 = (o[mt][nt][0] + Om[base      ]) * inv[nt];
                float v1 = (o[mt][nt][1] + Om[base +  64]) * inv[nt];
                float v2 = (o[mt][nt][2] + Om[base + 128]) * inv[nt];
                float v3 = (o[mt][nt][3] + Om[base + 192]) * inv[nt];
                int q = qt * 64 + nt * 16 + col;
                uint2 ov;
                ov.x = pk2(v0, v1);
                ov.y = pk2(v2, v3);
                *reinterpret_cast<uint2*>(ao + ((size_t)b * NX_ + q) * C_ +
                                          h * 64 + mt * 16 + quad * 4) = ov;
            }
    }
}

// ---------------- projection GEMM (4096x1024)x(1024x1024)^T, 128x64 tile ----------------
__global__ __launch_bounds__(256, 3) void proj_gemm_kernel(
    const unsigned short* __restrict__ abf,
    const unsigned short* __restrict__ wbf,
    const float* __restrict__ bias,
    float* __restrict__ out)
{
    __shared__ unsigned short As[128 * LSTR], Bs[64 * LSTR];
    int bn = blockIdx.x, bm = blockIdx.y;
    int w = threadIdx.x >> 6, l = threadIdx.x & 63;
    int quad = l >> 4, col = l & 15;
    int sarow = w * 32 + (l >> 2), sbrow = w * 16 + (l >> 2), schk = (l & 3) * 8;

    const unsigned short* Ap = abf + (size_t)(bm * 128 + sarow) * C_ + schk;
    const unsigned short* Bp = wbf + (size_t)(bn * 64 + sbrow) * C_ + schk;
    unsigned short* Aw = As + sarow * LSTR + schk;
    unsigned short* Bw = Bs + sbrow * LSTR + schk;

    f32x4 acc[2][4];
#pragma unroll
    for (int a = 0; a < 2; a++)
#pragma unroll
        for (int b = 0; b < 4; b++) acc[a][b] = (f32x4){0.f, 0.f, 0.f, 0.f};

    uint4 ar0, ar1, br0;
#define LDREG(kk_)                                                       \
    {   int kk = (kk_) * 32;                                             \
        ar0 = *reinterpret_cast<const uint4*>(Ap + kk);                  \
        ar1 = *reinterpret_cast<const uint4*>(Ap + 16 * C_ + kk);        \
        br0 = *reinterpret_cast<const uint4*>(Bp + kk);                  \
    }
#define WRTILE()                                                         \
    {   *reinterpret_cast<uint4*>(Aw)             = ar0;                 \
        *reinterpret_cast<uint4*>(Aw + 16 * LSTR) = ar1;                 \
        *reinterpret_cast<uint4*>(Bw)             = br0;                 \
    }

    LDREG(0);
    WRTILE();
    LDREG(1);
    __syncthreads();
#pragma unroll 1
    for (int it = 0; it < 32; it++) {
        bf16x8 af[2], bfr[4];
#pragma unroll
        for (int t = 0; t < 2; t++) af[t]  = ldfrag(&As[(w * 32 + t * 16 + col) * LSTR + quad * 8]);
#pragma unroll
        for (int t = 0; t < 4; t++) bfr[t] = ldfrag(&Bs[(t * 16 + col) * LSTR + quad * 8]);
#pragma unroll
        for (int mt = 0; mt < 2; mt++)
#pragma unroll
            for (int nt = 0; nt < 4; nt++)
                acc[mt][nt] = __builtin_amdgcn_mfma_f32_16x16x32_bf16(af[mt], bfr[nt], acc[mt][nt], 0, 0, 0);
        if (it < 31) {
            __syncthreads();
            WRTILE();
            LDREG(it + 2 < 31 ? it + 2 : 31);
            __syncthreads();
        }
    }
#undef LDREG
#undef WRTILE

    float bv[4];
#pragma unroll
    for (int nt = 0; nt < 4; nt++) bv[nt] = bias[bn * 64 + nt * 16 + col];
#pragma unroll
    for (int mt = 0; mt < 2; mt++)
#pragma unroll
        for (int r = 0; r < 4; r++) {
            int m = bm * 128 + w * 32 + mt * 16 + quad * 4 + r;
#pragma unroll
            for (int nt = 0; nt < 4; nt++) {
                int n = bn * 64 + nt * 16 + col;
                out[(size_t)m * C_ + n] = acc[mt][nt][r] + bv[nt];
            }
        }
}

extern "C" void kernel_launch(void* const* d_in, const int* in_sizes, int n_in,
                              void* d_out, int out_size, void* d_ws, size_t ws_size,
                              hipStream_t stream) {
    const float* x      = (const float*)d_in[0];
    const int*   uidx   = (const int*)  d_in[1];
    const float* cachek = (const float*)d_in[2];
    const float* cachev = (const float*)d_in[3];
    const float* wqkv   = (const float*)d_in[4];
    const float* bqkv   = (const float*)d_in[5];
    const float* wproj  = (const float*)d_in[6];
    const float* bproj  = (const float*)d_in[7];
    float* out = (float*)d_out;

    char* ws = (char*)d_ws;
    unsigned short* xbf  = (unsigned short*)(ws);                       // 8 MB
    unsigned short* wqbf = (unsigned short*)(ws + (8ull  << 20));       // 6 MB
    unsigned short* wpbf = (unsigned short*)(ws + (14ull << 20));       // 2 MB
    unsigned short* qb   = (unsigned short*)(ws + (16ull << 20));       // 8 MB
    unsigned short* kfb  = (unsigned short*)(ws + (24ull << 20));       // 16 MB
    unsigned short* vtb  = (unsigned short*)(ws + (40ull << 20));       // 16 MB
    unsigned short* aob  = (unsigned short*)(ws + (56ull << 20));       // 8 MB

    cvt_all_kernel<<<20480, 256, 0, stream>>>(x, wqkv, wproj, cachek, cachev,
                                              xbf, wqbf, wpbf, kfb, vtb);
    qkv_gemm_kernel <<<dim3(24, 32), 256, 0, stream>>>(xbf, wqbf, bqkv, uidx, qb, kfb, vtb);
    attn_kernel     <<<1024, 256, 0, stream>>>(qb, kfb, vtb, aob);
    proj_gemm_kernel<<<dim3(16, 32), 256, 0, stream>>>(aob, wpbf, bproj, out);
}

// Round 5
// 250.863 us; speedup vs baseline: 1.0704x; 1.0704x over previous
//
#include <hip/hip_runtime.h>
#include <hip/hip_bf16.h>

#define B_   4
#define NX_  1024
#define NC_  2048
#define C_   1024
#define H_   16
#define DH_  64

typedef __attribute__((ext_vector_type(8))) __bf16 bf16x8;
typedef __attribute__((ext_vector_type(4))) float  f32x4;

// RNE float->bf16 (inputs finite)
static __device__ __forceinline__ unsigned short f2bf(float f) {
    unsigned int u = __float_as_uint(f);
    u += 0x7fffu + ((u >> 16) & 1u);
    return (unsigned short)(u >> 16);
}

// pack 2 floats -> 2 bf16 (round-half-up): {lo in bits 0-15, hi in 16-31}
static __device__ __forceinline__ unsigned int pk2(float lo, float hi) {
    unsigned int a = __float_as_uint(lo) + 0x8000u;
    unsigned int b = __float_as_uint(hi) + 0x8000u;
    return __builtin_amdgcn_perm(b, a, 0x07060302);   // {b.hi16, a.hi16}
}

// 1-instr pack (RNE): dst.lo16 = bf16(lo), dst.hi16 = bf16(hi)
// (harness-proven in R2's v4 kernel feeding MFMA operands)
static __device__ __forceinline__ unsigned int cvtpk(float lo, float hi) {
    unsigned int r;
    asm("v_cvt_pk_bf16_f32 %0, %1, %2" : "=v"(r) : "v"(lo), "v"(hi));
    return r;
}

static __device__ __forceinline__ bf16x8 ldfrag(const unsigned short* p) {
    union { uint4 u; bf16x8 b; } cv;
    cv.u = *reinterpret_cast<const uint4*>(p);
    return cv.b;
}

// ---------------- merged converts: x, w_qkv, w_proj, cache_k (flat) + cache_v (transpose) ----------------
__global__ __launch_bounds__(256) void cvt_all_kernel(
    const float* __restrict__ x,  const float* __restrict__ wq,
    const float* __restrict__ wp, const float* __restrict__ ck,
    const float* __restrict__ cv_,
    unsigned short* __restrict__ xbf,  unsigned short* __restrict__ wqbf,
    unsigned short* __restrict__ wpbf, unsigned short* __restrict__ kfb,
    unsigned short* __restrict__ vt) {
    int blk = blockIdx.x;
    if (blk < 16384) {
        const float* src; unsigned short* dst; int i;
        if (blk < 4096)      { src = x;  dst = xbf;  i = blk; }
        else if (blk < 7168) { src = wq; dst = wqbf; i = blk - 4096; }
        else if (blk < 8192) { src = wp; dst = wpbf; i = blk - 7168; }
        else                 { src = ck; dst = kfb;  i = blk - 8192; }
        int idx = i * 256 + threadIdx.x;
        float4 f = reinterpret_cast<const float4*>(src)[idx];
        ushort4 o;
        o.x = f2bf(f.x); o.y = f2bf(f.y); o.z = f2bf(f.z); o.w = f2bf(f.w);
        reinterpret_cast<ushort4*>(dst)[idx] = o;
    } else {
        int i   = blk - 16384;       // 0..4095
        int t   = threadIdx.x;
        int bh  = i >> 6;
        int kg  = i & 63;
        int d   = t & 63;
        int kci = t >> 6;
        int kc  = kg * 4 + kci;
        const float* src = cv_ + ((size_t)bh * NC_ + (size_t)kc * 8) * DH_ + d;
        union { uint4 u; unsigned short s[8]; } o;
#pragma unroll
        for (int j = 0; j < 8; j++) o.s[j] = f2bf(src[(size_t)j * DH_]);
        *reinterpret_cast<uint4*>(vt + ((size_t)bh * DH_ + d) * NC_ + (size_t)kc * 8) = o.u;
    }
}

#define LSTR 40

// ---------------- QKV GEMM (4096x1024)x(3072x1024)^T, 128x128 tile + scatter ----------------
__global__ __launch_bounds__(256, 3) void qkv_gemm_kernel(
    const unsigned short* __restrict__ xbf,
    const unsigned short* __restrict__ wbf,
    const float* __restrict__ bias,
    const int* __restrict__ uidx,
    unsigned short* __restrict__ qb,   // (B,H,NX,DH) scaled by 0.125*log2(e)
    unsigned short* __restrict__ kf,   // (B,H,NC,DH)
    unsigned short* __restrict__ vt)   // (B,H,DH,NC)
{
    __shared__ unsigned short As[128 * LSTR], Bs[128 * LSTR];
    __shared__ int jtab[128];
    int bn = blockIdx.x, bm = blockIdx.y;
    int w = threadIdx.x >> 6, l = threadIdx.x & 63;
    int quad = l >> 4, col = l & 15;
    int wr = w >> 1, wc = w & 1;
    int srow = w * 32 + (l >> 2), schk = (l & 3) * 8;

    const unsigned short* Ap = xbf + (size_t)(bm * 128 + srow) * C_ + schk;
    const unsigned short* Bp = wbf + (size_t)(bn * 128 + srow) * C_ + schk;
    unsigned short* Aw = As + srow * LSTR + schk;
    unsigned short* Bw = Bs + srow * LSTR + schk;

    f32x4 acc[4][4];
#pragma unroll
    for (int a = 0; a < 4; a++)
#pragma unroll
        for (int b = 0; b < 4; b++) acc[a][b] = (f32x4){0.f, 0.f, 0.f, 0.f};

    uint4 ar0, ar1, br0, br1;
#define LDREG(kk_)                                                       \
    {   int kk = (kk_) * 32;                                             \
        ar0 = *reinterpret_cast<const uint4*>(Ap + kk);                  \
        ar1 = *reinterpret_cast<const uint4*>(Ap + 16 * C_ + kk);        \
        br0 = *reinterpret_cast<const uint4*>(Bp + kk);                  \
        br1 = *reinterpret_cast<const uint4*>(Bp + 16 * C_ + kk);        \
    }
#define WRTILE()                                                         \
    {   *reinterpret_cast<uint4*>(Aw)             = ar0;                 \
        *reinterpret_cast<uint4*>(Aw + 16 * LSTR) = ar1;                 \
        *reinterpret_cast<uint4*>(Bw)             = br0;                 \
        *reinterpret_cast<uint4*>(Bw + 16 * LSTR) = br1;                 \
    }

    LDREG(0);
    WRTILE();
    LDREG(1);
    __syncthreads();
#pragma unroll 1
    for (int it = 0; it < 32; it++) {
        bf16x8 af[4], bfr[4];
#pragma unroll
        for (int t = 0; t < 4; t++) af[t]  = ldfrag(&As[(wr * 64 + t * 16 + col) * LSTR + quad * 8]);
#pragma unroll
        for (int t = 0; t < 4; t++) bfr[t] = ldfrag(&Bs[(wc * 64 + t * 16 + col) * LSTR + quad * 8]);
#pragma unroll
        for (int mt = 0; mt < 4; mt++)
#pragma unroll
            for (int nt = 0; nt < 4; nt++)
                acc[mt][nt] = __builtin_amdgcn_mfma_f32_16x16x32_bf16(af[mt], bfr[nt], acc[mt][nt], 0, 0, 0);
        if (it < 31) {
            __syncthreads();
            WRTILE();
            LDREG(it + 2 < 31 ? it + 2 : 31);
            __syncthreads();
        }
    }
#undef LDREG
#undef WRTILE

    int part = bn >> 3;             // 0=q 1=k 2=v
    float bv[4];
#pragma unroll
    for (int nt = 0; nt < 4; nt++) bv[nt] = bias[bn * 128 + wc * 64 + nt * 16 + col];

    if (part <= 1) {
        int nl[4];
#pragma unroll
        for (int nt = 0; nt < 4; nt++) nl[nt] = (bn * 128 + wc * 64 + nt * 16 + col) & 1023;
        const float QS = 0.18033688011112042f;   // 0.125 * log2(e)
#pragma unroll
        for (int mt = 0; mt < 4; mt++)
#pragma unroll
            for (int r = 0; r < 4; r++) {
                int m = bm * 128 + wr * 64 + mt * 16 + quad * 4 + r;
                int b = m >> 10, i = m & 1023;
                int j = (part == 0) ? 0 : uidx[m];
#pragma unroll
                for (int nt = 0; nt < 4; nt++) {
                    int h = nl[nt] >> 6, d = nl[nt] & 63;
                    float v = acc[mt][nt][r] + bv[nt];
                    if (part == 0)
                        qb[((size_t)(b * H_ + h) * NX_ + i) * DH_ + d] = f2bf(v * QS);
                    else
                        kf[((size_t)(b * H_ + h) * NC_ + j) * DH_ + d] = f2bf(v);
                }
            }
    } else {
        // ---- V-part: LDS transpose + token-major scatter ----
        if (threadIdx.x < 128) jtab[threadIdx.x] = uidx[bm * 128 + threadIdx.x];
        __syncthreads();   // jtab ready; As/Bs reads from main loop done
        int h = ((bn * 128 + wc * 64) & 1023) >> 6;   // const per wave (64-aligned)
        int b = (bm * 128) >> 10;
        unsigned short* T = (wc == 0) ? As : Bs;      // 64 x 72 bf16 (9216 B)
        int jv = jtab[wr * 64 + l];
        unsigned short* vb2 = vt + ((size_t)(b * H_ + h) * 64) * NC_ + jv;
#pragma unroll 1
        for (int round = 0; round < 2; round++) {
            if (wr == round) {
#pragma unroll
                for (int nt = 0; nt < 4; nt++)
#pragma unroll
                    for (int mt = 0; mt < 4; mt++) {
                        uint2 pk;
                        pk.x = pk2(acc[mt][nt][0] + bv[nt], acc[mt][nt][1] + bv[nt]);
                        pk.y = pk2(acc[mt][nt][2] + bv[nt], acc[mt][nt][3] + bv[nt]);
                        *reinterpret_cast<uint2*>(&T[(nt * 16 + col) * 72 + mt * 16 + quad * 4]) = pk;
                    }
                asm volatile("s_waitcnt lgkmcnt(0)" ::: "memory");
#pragma unroll 1
                for (int d = 0; d < 64; d++)
                    vb2[(size_t)d * NC_] = T[d * 72 + l];   // lanes = 64 sorted tokens
            }
            __syncthreads();
        }
    }
}

// ---------------- flash attention v6: v3 structure + cvtpk pack + ones-MFMA l ----------------
// R3 post-mortem: v5 failed correctness; bisect -> only never-proven element was inline-asm
// v_exp_f32 (TRANS op; CDNA needs a manual wait state before the VALU consumer, and the
// compiler can't see into opaque asm -> stale read). cvtpk+ones-MFMA passed in v4, v3
// structure passed in R2. v6 = v5 with exp2f restored (compiler inserts the TRANS hazard
// wait states around its own v_exp_f32 lowering).
__global__ __launch_bounds__(256, 4) void attn_kernel(
    const unsigned short* __restrict__ qb,
    const unsigned short* __restrict__ kf,
    const unsigned short* __restrict__ vt,
    unsigned short* __restrict__ ao)          // (B,NX,C) bf16
{
    __shared__ __align__(16) char smem[20480];
    unsigned short* Klo = (unsigned short*)smem;          // 64 x 40 (keys x dh0-31)
    unsigned short* Khi = Klo + 64 * LSTR;                // dh 32-63
    unsigned short* V0s = Khi + 64 * LSTR;                // V^T permuted slots: dh x keys 0-31
    unsigned short* V1s = V0s + 64 * LSTR;                // keys 32-63
    float* Om = (float*)smem;                             // aliases tiles after loop: [qh][32][64]
    float* Lm = Om + 2 * 32 * 64;                         // [qh][nt][16]  (16640 B <= 20480)

    int id = blockIdx.x;
    int qt = (id >> 3) & 15;               // 0..15
    int bh = ((id >> 7) << 3) | (id & 7);  // 0..63, id%8 == bh%8 (XCD locality)
    int wave = threadIdx.x >> 6, lane = threadIdx.x & 63;
    int quad = lane >> 4, col = lane & 15;
    int qh = wave & 1;                     // query half (32 q)
    int kh = wave >> 1;                    // key half of each 64-key tile
    int srow = wave * 16 + (lane >> 2), schk = (lane & 3) * 8;
    int L = lane & 3;
    // sigma slot-chunk permutation: global key chunk c -> slot 2c (c<4) / 2c-7 (c>=4)
    int ve0 = (L < 2) ? 16 * L : 16 * L - 28;   // element offset of low 8B (keys schk..+3)
    int ve1 = ve0 + 8;                          // high 8B (keys schk+4..+7)

    // Q fragments: 2 q-16-tiles x 2 dh-halves
    const unsigned short* qrow0 = qb + ((size_t)bh * NX_ + qt * 64 + qh * 32 + col) * DH_;
    bf16x8 qfA[2], qfB[2];
    qfA[0] = ldfrag(qrow0 + quad * 8);
    qfB[0] = ldfrag(qrow0 + 32 + quad * 8);
    qfA[1] = ldfrag(qrow0 + 16 * DH_ + quad * 8);
    qfB[1] = ldfrag(qrow0 + 16 * DH_ + 32 + quad * 8);

    const unsigned short* Kp = kf + ((size_t)bh * NC_ + srow) * DH_ + schk;
    const unsigned short* Vp = vt + ((size_t)bh * DH_ + srow) * NC_ + schk;
    unsigned short* Kwl = Klo + srow * LSTR + schk;
    unsigned short* Kwh = Khi + srow * LSTR + schk;
    unsigned short* Vw0 = V0s + srow * LSTR;
    unsigned short* Vw1 = V1s + srow * LSTR;
    const unsigned short* Vs = kh ? V1s : V0s;
    int kq = kh * 32;

    f32x4 o[4][2];
#pragma unroll
    for (int m = 0; m < 4; m++)
#pragma unroll
        for (int n = 0; n < 2; n++) o[m][n] = (f32x4){0.f, 0.f, 0.f, 0.f};
    f32x4 lacc[2];
    lacc[0] = (f32x4){0.f, 0.f, 0.f, 0.f};
    lacc[1] = (f32x4){0.f, 0.f, 0.f, 0.f};
    bf16x8 onef;
    { union { unsigned int u[4]; bf16x8 b; } c1;
      c1.u[0] = c1.u[1] = c1.u[2] = c1.u[3] = 0x3F803F80u; onef = c1.b; }

    uint4 kr0, kr1, vr0, vr1;
#define LDREG(kb_)                                                        \
    {   kr0 = *reinterpret_cast<const uint4*>(Kp + (size_t)(kb_) * 64 * DH_);      \
        kr1 = *reinterpret_cast<const uint4*>(Kp + (size_t)(kb_) * 64 * DH_ + 32); \
        vr0 = *reinterpret_cast<const uint4*>(Vp + (kb_) * 64);           \
        vr1 = *reinterpret_cast<const uint4*>(Vp + (kb_) * 64 + 32);      \
    }
#define WRTILE()                                                          \
    {   *reinterpret_cast<uint4*>(Kwl) = kr0;                             \
        *reinterpret_cast<uint4*>(Kwh) = kr1;                             \
        uint2 t_;                                                         \
        t_.x = vr0.x; t_.y = vr0.y; *reinterpret_cast<uint2*>(Vw0 + ve0) = t_; \
        t_.x = vr0.z; t_.y = vr0.w; *reinterpret_cast<uint2*>(Vw0 + ve1) = t_; \
        t_.x = vr1.x; t_.y = vr1.y; *reinterpret_cast<uint2*>(Vw1 + ve0) = t_; \
        t_.x = vr1.z; t_.y = vr1.w; *reinterpret_cast<uint2*>(Vw1 + ve1) = t_; \
    }

    LDREG(0);
    WRTILE();
    LDREG(1);
    __syncthreads();

#pragma unroll 1
    for (int kb = 0; kb < 32; kb++) {
        // ---- S^T = K.Q^T : 32 keys (kh half) x 32 queries ----
        f32x4 s[2][2];
#pragma unroll
        for (int mt = 0; mt < 2; mt++)
#pragma unroll
            for (int nt = 0; nt < 2; nt++) s[mt][nt] = (f32x4){0.f, 0.f, 0.f, 0.f};
#pragma unroll
        for (int mt = 0; mt < 2; mt++) {
            bf16x8 ka = ldfrag(&Klo[(kq + mt * 16 + col) * LSTR + quad * 8]);
            bf16x8 kb_ = ldfrag(&Khi[(kq + mt * 16 + col) * LSTR + quad * 8]);
#pragma unroll
            for (int nt = 0; nt < 2; nt++) {
                s[mt][nt] = __builtin_amdgcn_mfma_f32_16x16x32_bf16(ka,  qfA[nt], s[mt][nt], 0, 0, 0);
                s[mt][nt] = __builtin_amdgcn_mfma_f32_16x16x32_bf16(kb_, qfB[nt], s[mt][nt], 0, 0, 0);
            }
        }
        // ---- V fragments (issued early; read slot order == storage order) ----
        bf16x8 vfr[4];
#pragma unroll
        for (int t = 0; t < 4; t++) vfr[t] = ldfrag(&Vs[(t * 16 + col) * LSTR + quad * 8]);
        // ---- no-max softmax (log2 domain) -> B-fragment directly in registers ----
        bf16x8 pf[2];
#pragma unroll
        for (int nt = 0; nt < 2; nt++) {
            float e0 = exp2f(s[0][nt][0]), e1 = exp2f(s[0][nt][1]);
            float e2 = exp2f(s[0][nt][2]), e3 = exp2f(s[0][nt][3]);
            float e4 = exp2f(s[1][nt][0]), e5 = exp2f(s[1][nt][1]);
            float e6 = exp2f(s[1][nt][2]), e7 = exp2f(s[1][nt][3]);
            union { unsigned int u[4]; bf16x8 b; } pw;
            pw.u[0] = cvtpk(e0, e1);   // slots 8q,8q+1  = keys 4q,4q+1
            pw.u[1] = cvtpk(e2, e3);   // slots 8q+2,3   = keys 4q+2,4q+3
            pw.u[2] = cvtpk(e4, e5);   // slots 8q+4,5   = keys 16+4q,+1
            pw.u[3] = cvtpk(e6, e7);   // slots 8q+6,7   = keys 16+4q+2,+3
            pf[nt] = pw.b;
        }
        // ---- l via ones-row MFMA (sum over slots == sum over keys) ----
        lacc[0] = __builtin_amdgcn_mfma_f32_16x16x32_bf16(onef, pf[0], lacc[0], 0, 0, 0);
        lacc[1] = __builtin_amdgcn_mfma_f32_16x16x32_bf16(onef, pf[1], lacc[1], 0, 0, 0);
        // ---- O^T += V^T . P^T  (V columns permuted to match) ----
#pragma unroll
        for (int mt = 0; mt < 4; mt++) {
            o[mt][0] = __builtin_amdgcn_mfma_f32_16x16x32_bf16(vfr[mt], pf[0], o[mt][0], 0, 0, 0);
            o[mt][1] = __builtin_amdgcn_mfma_f32_16x16x32_bf16(vfr[mt], pf[1], o[mt][1], 0, 0, 0);
        }
        if (kb < 31) {
            __syncthreads();
            WRTILE();
            LDREG(kb + 2 < 31 ? kb + 2 : 31);
            __syncthreads();
        }
    }
#undef LDREG
#undef WRTILE

    // l_i: every element of lacc[nt] is the full 32-key-slice sum for query col
    float l_i[2] = { lacc[0][0], lacc[1][0] };

    // ---- merge key halves: plain (O,l) addition (m==0 softmax) ----
    __syncthreads();   // tile reads done; smem reused as Om/Lm
    if (kh == 1) {
#pragma unroll
        for (int mt = 0; mt < 4; mt++)
#pragma unroll
            for (int nt = 0; nt < 2; nt++)
#pragma unroll
                for (int r = 0; r < 4; r++)
                    Om[(qh * 32 + (mt * 2 + nt) * 4 + r) * 64 + lane] = o[mt][nt][r];
        if (quad == 0) {
            Lm[(qh * 2 + 0) * 16 + col] = l_i[0];
            Lm[(qh * 2 + 1) * 16 + col] = l_i[1];
        }
    }
    __syncthreads();
    if (kh == 0) {
        float inv[2];
#pragma unroll
        for (int nt = 0; nt < 2; nt++)
            inv[nt] = 1.f / (l_i[nt] + Lm[(qh * 2 + nt) * 16 + col]);
        int b = bh >> 4, h = bh & 15;
#pragma unroll
        for (int mt = 0; mt < 4; mt++)
#pragma unroll
            for (int nt = 0; nt < 2; nt++) {
                int base = (qh * 32 + (mt * 2 + nt) * 4) * 64 + lane;
                float v0 = (o[mt][nt][0] + Om[base])       * inv[nt];
                float v1 = (o[mt][nt][1] + Om[base + 64])  * inv[nt];
                float v2 = (o[mt][nt][2] + Om[base + 128]) * inv[nt];
                float v3 = (o[mt][nt][3] + Om[base + 192]) * inv[nt];
                int q = qt * 64 + qh * 32 + nt * 16 + col;
                uint2 ov;
                ov.x = pk2(v0, v1);
                ov.y = pk2(v2, v3);
                *reinterpret_cast<uint2*>(ao + ((size_t)b * NX_ + q) * C_ +
                                          h * 64 + mt * 16 + quad * 4) = ov;
            }
    }
}

// ---------------- projection GEMM (4096x1024)x(1024x1024)^T, 128x64 tile ----------------
__global__ __launch_bounds__(256, 3) void proj_gemm_kernel(
    const unsigned short* __restrict__ abf,
    const unsigned short* __restrict__ wbf,
    const float* __restrict__ bias,
    float* __restrict__ out)
{
    __shared__ unsigned short As[128 * LSTR], Bs[64 * LSTR];
    int bn = blockIdx.x, bm = blockIdx.y;
    int w = threadIdx.x >> 6, l = threadIdx.x & 63;
    int quad = l >> 4, col = l & 15;
    int sarow = w * 32 + (l >> 2), sbrow = w * 16 + (l >> 2), schk = (l & 3) * 8;

    const unsigned short* Ap = abf + (size_t)(bm * 128 + sarow) * C_ + schk;
    const unsigned short* Bp = wbf + (size_t)(bn * 64 + sbrow) * C_ + schk;
    unsigned short* Aw = As + sarow * LSTR + schk;
    unsigned short* Bw = Bs + sbrow * LSTR + schk;

    f32x4 acc[2][4];
#pragma unroll
    for (int a = 0; a < 2; a++)
#pragma unroll
        for (int b = 0; b < 4; b++) acc[a][b] = (f32x4){0.f, 0.f, 0.f, 0.f};

    uint4 ar0, ar1, br0;
#define LDREG(kk_)                                                       \
    {   int kk = (kk_) * 32;                                             \
        ar0 = *reinterpret_cast<const uint4*>(Ap + kk);                  \
        ar1 = *reinterpret_cast<const uint4*>(Ap + 16 * C_ + kk);        \
        br0 = *reinterpret_cast<const uint4*>(Bp + kk);                  \
    }
#define WRTILE()                                                         \
    {   *reinterpret_cast<uint4*>(Aw)             = ar0;                 \
        *reinterpret_cast<uint4*>(Aw + 16 * LSTR) = ar1;                 \
        *reinterpret_cast<uint4*>(Bw)             = br0;                 \
    }

    LDREG(0);
    WRTILE();
    LDREG(1);
    __syncthreads();
#pragma unroll 1
    for (int it = 0; it < 32; it++) {
        bf16x8 af[2], bfr[4];
#pragma unroll
        for (int t = 0; t < 2; t++) af[t]  = ldfrag(&As[(w * 32 + t * 16 + col) * LSTR + quad * 8]);
#pragma unroll
        for (int t = 0; t < 4; t++) bfr[t] = ldfrag(&Bs[(t * 16 + col) * LSTR + quad * 8]);
#pragma unroll
        for (int mt = 0; mt < 2; mt++)
#pragma unroll
            for (int nt = 0; nt < 4; nt++)
                acc[mt][nt] = __builtin_amdgcn_mfma_f32_16x16x32_bf16(af[mt], bfr[nt], acc[mt][nt], 0, 0, 0);
        if (it < 31) {
            __syncthreads();
            WRTILE();
            LDREG(it + 2 < 31 ? it + 2 : 31);
            __syncthreads();
        }
    }
#undef LDREG
#undef WRTILE

    float bv[4];
#pragma unroll
    for (int nt = 0; nt < 4; nt++) bv[nt] = bias[bn * 64 + nt * 16 + col];
#pragma unroll
    for (int mt = 0; mt < 2; mt++)
#pragma unroll
        for (int r = 0; r < 4; r++) {
            int m = bm * 128 + w * 32 + mt * 16 + quad * 4 + r;
#pragma unroll
            for (int nt = 0; nt < 4; nt++) {
                int n = bn * 64 + nt * 16 + col;
                out[(size_t)m * C_ + n] = acc[mt][nt][r] + bv[nt];
            }
        }
}

extern "C" void kernel_launch(void* const* d_in, const int* in_sizes, int n_in,
                              void* d_out, int out_size, void* d_ws, size_t ws_size,
                              hipStream_t stream) {
    const float* x      = (const float*)d_in[0];
    const int*   uidx   = (const int*)  d_in[1];
    const float* cachek = (const float*)d_in[2];
    const float* cachev = (const float*)d_in[3];
    const float* wqkv   = (const float*)d_in[4];
    const float* bqkv   = (const float*)d_in[5];
    const float* wproj  = (const float*)d_in[6];
    const float* bproj  = (const float*)d_in[7];
    float* out = (float*)d_out;

    char* ws = (char*)d_ws;
    unsigned short* xbf  = (unsigned short*)(ws);                       // 8 MB
    unsigned short* wqbf = (unsigned short*)(ws + (8ull  << 20));       // 6 MB
    unsigned short* wpbf = (unsigned short*)(ws + (14ull << 20));       // 2 MB
    unsigned short* qb   = (unsigned short*)(ws + (16ull << 20));       // 8 MB
    unsigned short* kfb  = (unsigned short*)(ws + (24ull << 20));       // 16 MB
    unsigned short* vtb  = (unsigned short*)(ws + (40ull << 20));       // 16 MB
    unsigned short* aob  = (unsigned short*)(ws + (56ull << 20));       // 8 MB

    cvt_all_kernel<<<20480, 256, 0, stream>>>(x, wqkv, wproj, cachek, cachev,
                                              xbf, wqbf, wpbf, kfb, vtb);
    qkv_gemm_kernel <<<dim3(24, 32), 256, 0, stream>>>(xbf, wqbf, bqkv, uidx, qb, kfb, vtb);
    attn_kernel     <<<1024, 256, 0, stream>>>(qb, kfb, vtb, aob);
    proj_gemm_kernel<<<dim3(16, 32), 256, 0, stream>>>(aob, wpbf, bproj, out);
}